// Round 4
// baseline (409.811 us; speedup 1.0000x reference)
//
#include <hip/hip_runtime.h>
#include <hip/hip_bf16.h>
#include <math.h>

#define NB 256
#define SS 512
#define LL 128

typedef short bf16x4 __attribute__((ext_vector_type(4)));
typedef float f32x4 __attribute__((ext_vector_type(4)));

__device__ __forceinline__ short f2bf(float f) {
    __hip_bfloat16 h = __float2bfloat16(f);
    short s;
    __builtin_memcpy(&s, &h, 2);
    return s;
}

// D = A*B + C for 16x16x16 bf16. C/D layout (row=4*hi+reg, col=lo) is
// IDENTICAL to the B layout (k=4*hi+j, col=lo) -> the output of one round is
// directly the B operand of the next: the recurrence never leaves registers.
#if __has_builtin(__builtin_amdgcn_mfma_f32_16x16x16bf16_1k)
#define MFMA1616(c, a, bb) \
    c = __builtin_amdgcn_mfma_f32_16x16x16bf16_1k(a, bb, c, 0, 0, 0)
#else
#define MFMA1616(c, a, bb) \
    asm("v_mfma_f32_16x16x16_bf16 %0, %1, %2, %0" : "+v"(c) : "v"(a), "v"(bb))
#endif

// One WAVE = one chain (fwd or bwd) of one batch, recurrence fully in
// registers (round-3 structure, verified absmax 0.0). Round-4 change: pack
// 8 waves (8 independent chains) per 512-thread block, grid 64 -> 1 block/CU
// -> 8 waves/CU -> 2 waves/SIMD. The ~1060 cyc/round of dependency stall
// that round 3 exposed (1 wave/SIMD) is now filled by the co-resident wave's
// MFMA/VALU issue. No barriers anywhere; per-wave LDS regions.
template <int ISB>
__device__ __forceinline__ void run_chain(
    const int lane,                     // 0..63 within this wave
    const float* __restrict__ fb,       // this batch's features (S,L)
    const float* __restrict__ start_t,
    const float* __restrict__ end_t,
    const float* __restrict__ trans,
    float* __restrict__ eRing,          // per-wave LDS [4*LL]
    const int* __restrict__ lmask,      // per-wave LDS [SS]
    float* __restrict__ outv,           // av/bv row (L floats)
    float* __restrict__ oute)           // eFa/eBa slot
{
    const int lo = lane & 15;
    const int hi = lane >> 4;

    // ---- A-fragments: exp(transition), whole 128x128 in VGPRs ----
    // fwd: out[n] = sum_k exp(T[k][n]) u[k]  -> A[i=n][k] = exp(T[k][n])
    // bwd: out[i] = sum_j exp(T[i][j]) u[j]  -> A[i][k=j] = exp(T[i][j])
    bf16x4 Af[8][8];
#pragma unroll
    for (int nt = 0; nt < 8; ++nt) {
#pragma unroll
        for (int kt = 0; kt < 8; ++kt) {
            bf16x4 fr;
#pragma unroll
            for (int j = 0; j < 4; ++j) {
                const int kpos = 16 * kt + 4 * hi + j;
                const int npos = 16 * nt + lo;
                const float tv = ISB ? trans[npos * LL + kpos]
                                     : trans[kpos * LL + npos];
                fr[j] = f2bf(__expf(tv));
            }
            Af[nt][kt] = fr;
        }
    }

    // ---- state init (f32, canonical) + B-fragment init (bf16) ----
    float v[8][4];
    bf16x4 Bf[8];
#pragma unroll
    for (int nt = 0; nt < 8; ++nt) {
        bf16x4 fr;
#pragma unroll
        for (int j = 0; j < 4; ++j) {
            const int p = 16 * nt + 4 * hi + j;
            if (ISB) {
                const float val = __expf(end_t[p]);            // beta_511
                v[nt][j] = val;
                fr[j] = f2bf(val * __expf(fb[(size_t)511 * LL + p]));  // pub_0
            } else {
                const float val = __expf(start_t[p] + fb[p]);  // alpha_0
                v[nt][j] = val;
                fr[j] = f2bf(val);
            }
        }
        Bf[nt] = fr;
    }

    // ---- feature-exp ring prologue ----
    // row consumed at round r: fwd r+1, bwd 510-r. Slot r&3 holds that row.
    {
        const int r0 = ISB ? 510 : 1;   // round 0
        const int r1 = ISB ? 509 : 2;   // round 1
        const float2 a = *(const float2*)(fb + (size_t)r0 * LL + 2 * lane);
        const float2 bq = *(const float2*)(fb + (size_t)r1 * LL + 2 * lane);
        *(float2*)(eRing + 0 * LL + 2 * lane) = make_float2(__expf(a.x), __expf(a.y));
        *(float2*)(eRing + 1 * LL + 2 * lane) = make_float2(__expf(bq.x), __expf(bq.y));
    }
    float2 cur = *(const float2*)(fb + (size_t)(ISB ? 508 : 3) * LL + 2 * lane);
    float2 nxt = *(const float2*)(fb + (size_t)(ISB ? 507 : 4) * LL + 2 * lane);

    int eacc = 0;

    for (int r = 0; r < 256; ++r) {
        // ---- eft for THIS round: 8 broadcast ds_read_b128 from slot r&3
        //      (written 2 rounds ago; consumed after the MFMA block) ----
        const float* rp = eRing + (r & 3) * LL + 4 * hi;
        f32x4 eft[8];
#pragma unroll
        for (int nt = 0; nt < 8; ++nt)
            eft[nt] = *(const f32x4*)(rp + 16 * nt);

        // ---- pipeline: exp+publish row for round r+2; prefetch row r+4 ----
        *(float2*)(eRing + ((r + 2) & 3) * LL + 2 * lane) =
            make_float2(__expf(cur.x), __expf(cur.y));
        cur = nxt;
        {
            const int rowN = ISB ? (506 - r) : (r + 5);  // always in [0,512)
            nxt = *(const float2*)(fb + (size_t)rowN * LL + 2 * lane);
        }

        int mt = lmask[ISB ? (511 - r) : (r + 1)];

        // ---- 64 MFMAs: cc[nt] += A[nt][kt] * B[kt], 8 indep chains ----
        f32x4 cc[8];
#pragma unroll
        for (int nt = 0; nt < 8; ++nt) cc[nt] = (f32x4){0.f, 0.f, 0.f, 0.f};
#pragma unroll
        for (int kt = 0; kt < 8; ++kt) {
#pragma unroll
            for (int nt = 0; nt < 8; ++nt)
                MFMA1616(cc[nt], Af[nt][kt], Bf[kt]);
        }

        if (!ISB && r == 255) mt = 0;  // fwd dummy round

        // ---- epilogue, all in registers ----
        // fwd: cand = exp(f_t) * (T^T u);  bwd: cand = T * pub
#pragma unroll
        for (int nt = 0; nt < 8; ++nt) {
#pragma unroll
            for (int j = 0; j < 4; ++j) {
                const float cand = ISB ? cc[nt][j] : eft[nt][j] * cc[nt][j];
                v[nt][j] = mt ? cand : v[nt][j];
            }
        }

        // exp(features) ring rotation continues above; rescale below.

        // ---- exact power-of-2 rescale every 8 rounds ----
        if ((r & 7) == 7) {
            float s = 0.f;
#pragma unroll
            for (int nt = 0; nt < 8; ++nt)
#pragma unroll
                for (int j = 0; j < 4; ++j) s += v[nt][j];
            s += __shfl_xor(s, 16);   // combine hi groups (cols are replicas)
            s += __shfl_xor(s, 32);
            int ex;
            frexpf(s, &ex);
#pragma unroll
            for (int nt = 0; nt < 8; ++nt)
#pragma unroll
                for (int j = 0; j < 4; ++j) v[nt][j] = ldexpf(v[nt][j], -ex);
            eacc += ex;
        }

        // ---- pack next B: fwd publishes state; bwd publishes exp(f)*state ----
#pragma unroll
        for (int nt = 0; nt < 8; ++nt) {
            bf16x4 fr;
#pragma unroll
            for (int j = 0; j < 4; ++j)
                fr[j] = f2bf(ISB ? eft[nt][j] * v[nt][j] : v[nt][j]);
            Bf[nt] = fr;
        }
    }

    // ---- export (cols are replicas: lo==0 lanes write) ----
    if (lo == 0) {
#pragma unroll
        for (int nt = 0; nt < 8; ++nt) {
            f32x4 o = {v[nt][0], v[nt][1], v[nt][2], v[nt][3]};
            *(f32x4*)(outv + 16 * nt + 4 * hi) = o;
        }
    }
    if (lane == 0) *oute = (float)eacc;
}

__global__ __launch_bounds__(512, 2) void crf_chain_kernel(
    const float* __restrict__ feats,    // (B,S,L)
    const float* __restrict__ start_t,  // (L)
    const float* __restrict__ end_t,    // (L)
    const float* __restrict__ trans,    // (L,L)
    const int* __restrict__ mask,       // (B,S)
    const int* __restrict__ labels,     // (B,S)
    float* __restrict__ ws)
{
    const int wv = threadIdx.x >> 6;    // wave 0..7 within block
    const int lane = threadIdx.x & 63;
    const int cid = blockIdx.x * 8 + wv;  // chain id 0..511
    const int b = cid & 255;
    const int isB = cid >> 8;           // 0 = forward chain, 1 = backward chain

    __shared__ __align__(16) float eRing[8][4 * LL];  // 16 KB (2 KB/wave)
    __shared__ int lmask[8][SS];                      // 16 KB (2 KB/wave)

    // stage this wave's mask row (same-wave LDS; in-order DS makes RAW safe)
#pragma unroll
    for (int q = 0; q < 8; ++q)
        lmask[wv][lane + 64 * q] = mask[b * SS + lane + 64 * q];

    const float* fb = feats + (size_t)b * SS * LL;

    float* av = ws;                      // alpha_255 (B,L)
    float* bv = ws + NB * LL;            // beta_255  (B,L)
    float* eFa = ws + 2 * NB * LL;       // fwd exponents (B)
    float* eBa = eFa + NB;               // bwd exponents (B)
    float* lognum = eBa + NB;            // numerator (B)

    if (isB)
        run_chain<1>(lane, fb, start_t, end_t, trans, eRing[wv], lmask[wv],
                     bv + b * LL, eBa + b);
    else
        run_chain<0>(lane, fb, start_t, end_t, trans, eRing[wv], lmask[wv],
                     av + b * LL, eFa + b);

    // ---- numerator (gold path, fp32 exact), bwd waves only ----
    if (isB) {
        const int* lb = labels + b * SS;
        const int* mb = mask + b * SS;
        float term = 0.f;
        int cnt = 0;
#pragma unroll
        for (int q = 0; q < 8; ++q) {
            const int tt = lane + 64 * q;
            int l = lb[tt];
            if ((unsigned)l >= LL) l = 0;
            const int m = mb[tt];
            cnt += (m != 0);
            if (tt == 0) {
                term += start_t[l] + fb[l];
            } else if (m) {
                int lp = lb[tt - 1];
                if ((unsigned)lp >= LL) lp = 0;
                term += trans[lp * LL + l] + fb[(size_t)tt * LL + l];
            }
        }
#pragma unroll
        for (int o = 1; o < 64; o <<= 1) {
            term += __shfl_xor(term, o);
            cnt += __shfl_xor(cnt, o);
        }
        if (lane == 0) {
            int sl = cnt - 1;
            sl = sl < 0 ? 0 : (sl >= SS ? SS - 1 : sl);
            int lt = lb[sl];
            if ((unsigned)lt >= LL) lt = 0;
            lognum[b] = term + end_t[lt];
        }
    }
}

// Combine: Z = sum_i alpha_255[i]*beta_255[i] * 2^(eF+eB); loss reduce.
__global__ __launch_bounds__(256) void crf_final_kernel(
    const float* __restrict__ ws, const float* __restrict__ conf,
    float* __restrict__ out)
{
    const int tid = threadIdx.x;  // = batch index
    const float* av = ws;
    const float* bv = ws + NB * LL;
    const float* eFa = ws + 2 * NB * LL;
    const float* eBa = eFa + NB;
    const float* ln = eBa + NB;

    const float4* a4 = (const float4*)(av + tid * LL);
    const float4* b4 = (const float4*)(bv + tid * LL);
    float dot = 0.f;
#pragma unroll 8
    for (int k = 0; k < 32; ++k) {
        float4 a = a4[k], bb = b4[k];
        dot += a.x * bb.x + a.y * bb.y + a.z * bb.z + a.w * bb.w;
    }
    float logZ = logf(dot) + 0.69314718055994531f * (eFa[tid] + eBa[tid]);
    float loss = (logZ - ln[tid]) * conf[tid] * (1.0f / NB);

#pragma unroll
    for (int o = 1; o < 64; o <<= 1) loss += __shfl_xor(loss, o);
    __shared__ float red[4];
    if ((tid & 63) == 0) red[tid >> 6] = loss;
    __syncthreads();
    if (tid == 0) out[0] = red[0] + red[1] + red[2] + red[3];
}

extern "C" void kernel_launch(void* const* d_in, const int* in_sizes, int n_in,
                              void* d_out, int out_size, void* d_ws, size_t ws_size,
                              hipStream_t stream) {
    const float* feats  = (const float*)d_in[0];
    const float* startt = (const float*)d_in[1];
    const float* endt   = (const float*)d_in[2];
    const float* trans  = (const float*)d_in[3];
    const float* conf   = (const float*)d_in[4];
    const int*   mask   = (const int*)d_in[5];
    const int*   labels = (const int*)d_in[6];
    float* out = (float*)d_out;
    float* ws = (float*)d_ws;  // needs (2*256*128 + 3*256) floats = ~266 KB

    hipLaunchKernelGGL(crf_chain_kernel, dim3(64), dim3(512), 0, stream,
                       feats, startt, endt, trans, mask, labels, ws);
    hipLaunchKernelGGL(crf_final_kernel, dim3(1), dim3(256), 0, stream,
                       ws, conf, out);
}

// Round 5
// 252.568 us; speedup vs baseline: 1.6226x; 1.6226x over previous
//
#include <hip/hip_runtime.h>
#include <hip/hip_bf16.h>
#include <math.h>

#define NB 256
#define SS 512
#define LL 128

typedef short bf16x8 __attribute__((ext_vector_type(8)));
typedef float f32x4 __attribute__((ext_vector_type(4)));

__device__ __forceinline__ short f2bf(float f) {
    __hip_bfloat16 h = __float2bfloat16(f);
    short s;
    __builtin_memcpy(&s, &h, 2);
    return s;
}

// In-register CRF recurrence with 16x16x32 bf16 MFMA.
// Hardware pairs A-slot (g',j) with B-slot (g',j) (both layouts use
// k = 8*(lane>>4)+j; verified by the m92/m97-style GEMMs). Therefore any
// bijection state-row -> slot works if A is filled consistently. We choose
// the ZERO-MOVE packing: B tile kt slot j <- D value v[2kt+(j>>2)][j&3]
// (lane keeps its own registers; no cross-lane ops). The matching A fill:
// tile (nt,kt) slot j holds exp(T)[row(kt,hi,j)][16nt+lo] (fwd) where
// row(kt,hi,j) = 32kt + 16*(j>>2) + 4*hi + (j&3).
#define MFMA1632(c, a, bb) \
    c = __builtin_amdgcn_mfma_f32_16x16x32_bf16(a, bb, c, 0, 0, 0)

// One WAVE = one chain (fwd or bwd) of one batch; grid 512 (2 blocks/CU).
// Recurrence fully in registers (round-3 verified structure). Round-5
// changes: (1) K=32 MFMA -> 32 MFMAs/round (was 64 K=16), zero-repack
// chaining per the slot convention above; (2) raw-feature prefetch depth 2
// rounds (nxt0/nxt1) so the global load latency (~200-900 cy) is off the
// critical path. No barriers anywhere.
template <int ISB>
__device__ __forceinline__ void run_chain(
    const int lane,
    const float* __restrict__ fb,       // this batch's features (S,L)
    const float* __restrict__ start_t,
    const float* __restrict__ end_t,
    const float* __restrict__ trans,
    float* __restrict__ eRing,          // per-wave LDS [4*LL]
    const int* __restrict__ lmask,      // per-wave LDS [SS]
    float* __restrict__ outv,           // av/bv row (L floats)
    float* __restrict__ oute)           // eFa/eBa slot
{
    const int lo = lane & 15;
    const int hi = lane >> 4;

    // ---- A-fragments: exp(transition), whole 128x128 in VGPRs (128) ----
    // fwd: out[n] = sum_k exp(T[k][n]) u[k];  bwd: out[i] = sum_j exp(T[i][j]) u[j]
    bf16x8 Af[8][4];
#pragma unroll
    for (int nt = 0; nt < 8; ++nt) {
#pragma unroll
        for (int kt = 0; kt < 4; ++kt) {
            bf16x8 fr;
#pragma unroll
            for (int j = 0; j < 8; ++j) {
                const int r = 32 * kt + 16 * (j >> 2) + 4 * hi + (j & 3);
                const int n = 16 * nt + lo;
                const float tv = ISB ? trans[n * LL + r] : trans[r * LL + n];
                fr[j] = f2bf(__expf(tv));
            }
            Af[nt][kt] = fr;
        }
    }

    // ---- state init (f32, D layout: v[nt][reg] = row 16nt+4hi+reg) ----
    float v[8][4];
#pragma unroll
    for (int nt = 0; nt < 8; ++nt) {
#pragma unroll
        for (int j = 0; j < 4; ++j) {
            const int p = 16 * nt + 4 * hi + j;
            if (ISB) {
                v[nt][j] = __expf(end_t[p]);            // beta_511
            } else {
                v[nt][j] = __expf(start_t[p] + fb[p]);  // alpha_0
            }
        }
    }

    // ---- B-fragment init: slot j of tile kt = pub[2kt+(j>>2)][j&3] ----
    // fwd publishes alpha; bwd publishes exp(f_511)*beta
    bf16x8 Bf[4];
#pragma unroll
    for (int kt = 0; kt < 4; ++kt) {
        bf16x8 fr;
#pragma unroll
        for (int j = 0; j < 8; ++j) {
            const int nt = 2 * kt + (j >> 2);
            const int reg = j & 3;
            float val = v[nt][reg];
            if (ISB) val *= __expf(fb[(size_t)511 * LL + 16 * nt + 4 * hi + reg]);
            fr[j] = f2bf(val);
        }
        Bf[kt] = fr;
    }

    // ---- feature ring prologue ----
    // row(r): fwd r+1, bwd 510-r. Ring slot r&3 holds exp(row(r)).
    {
        const int r0 = ISB ? 510 : 1;
        const int r1 = ISB ? 509 : 2;
        const float2 a = *(const float2*)(fb + (size_t)r0 * LL + 2 * lane);
        const float2 bq = *(const float2*)(fb + (size_t)r1 * LL + 2 * lane);
        *(float2*)(eRing + 0 * LL + 2 * lane) = make_float2(__expf(a.x), __expf(a.y));
        *(float2*)(eRing + 1 * LL + 2 * lane) = make_float2(__expf(bq.x), __expf(bq.y));
    }
    // raw rows for rounds r+2, r+3 in flight (2-round latency budget)
    float2 nxt0 = *(const float2*)(fb + (size_t)(ISB ? 508 : 3) * LL + 2 * lane);
    float2 nxt1 = *(const float2*)(fb + (size_t)(ISB ? 507 : 4) * LL + 2 * lane);

    int eacc = 0;

    for (int r = 0; r < 256; ++r) {
        // ---- eft for THIS round: 8 broadcast ds_read_b128 (slot r&3,
        //      written 2 rounds ago); consumed after the MFMA block ----
        const float* rp = eRing + (r & 3) * LL + 4 * hi;
        f32x4 eft[8];
#pragma unroll
        for (int nt = 0; nt < 8; ++nt)
            eft[nt] = *(const f32x4*)(rp + 16 * nt);

        // ---- ring rotate: exp+publish row(r+2) (loaded 2 rounds ago);
        //      shift; prefetch raw row(r+4) ----
        *(float2*)(eRing + ((r + 2) & 3) * LL + 2 * lane) =
            make_float2(__expf(nxt0.x), __expf(nxt0.y));
        nxt0 = nxt1;
        {
            const int rowN = ISB ? (506 - r) : (r + 5);  // stays in [0,512)
            nxt1 = *(const float2*)(fb + (size_t)rowN * LL + 2 * lane);
        }

        int mt = lmask[ISB ? (511 - r) : (r + 1)];

        // ---- 32 MFMAs: cc[nt] += A[nt][kt] * B[kt], 8 indep chains ----
        f32x4 cc[8];
#pragma unroll
        for (int nt = 0; nt < 8; ++nt) cc[nt] = (f32x4){0.f, 0.f, 0.f, 0.f};
#pragma unroll
        for (int kt = 0; kt < 4; ++kt) {
#pragma unroll
            for (int nt = 0; nt < 8; ++nt)
                MFMA1632(cc[nt], Af[nt][kt], Bf[kt]);
        }

        if (!ISB && r == 255) mt = 0;  // fwd dummy round

        // ---- epilogue in registers ----
        // fwd: cand = exp(f_t)*(T^T u); bwd: cand = T*pub
#pragma unroll
        for (int nt = 0; nt < 8; ++nt) {
#pragma unroll
            for (int j = 0; j < 4; ++j) {
                const float cand = ISB ? cc[nt][j] : eft[nt][j] * cc[nt][j];
                v[nt][j] = mt ? cand : v[nt][j];
            }
        }

        // ---- exact power-of-2 rescale every 8 rounds ----
        if ((r & 7) == 7) {
            float s = 0.f;
#pragma unroll
            for (int nt = 0; nt < 8; ++nt)
#pragma unroll
                for (int j = 0; j < 4; ++j) s += v[nt][j];
            s += __shfl_xor(s, 16);   // combine hi groups (cols are replicas)
            s += __shfl_xor(s, 32);
            int ex;
            frexpf(s, &ex);
#pragma unroll
            for (int nt = 0; nt < 8; ++nt)
#pragma unroll
                for (int j = 0; j < 4; ++j) v[nt][j] = ldexpf(v[nt][j], -ex);
            eacc += ex;
        }

        // ---- pack next B (zero-move): slot j <- pub[2kt+(j>>2)][j&3] ----
        // fwd publishes state; bwd publishes exp(f_t)*state
#pragma unroll
        for (int kt = 0; kt < 4; ++kt) {
            bf16x8 fr;
#pragma unroll
            for (int j = 0; j < 8; ++j) {
                const int nt = 2 * kt + (j >> 2);
                const int reg = j & 3;
                const float val = ISB ? eft[nt][reg] * v[nt][reg] : v[nt][reg];
                fr[j] = f2bf(val);
            }
            Bf[kt] = fr;
        }
    }

    // ---- export (cols are replicas: lo==0 lanes write) ----
    if (lo == 0) {
#pragma unroll
        for (int nt = 0; nt < 8; ++nt) {
            f32x4 o = {v[nt][0], v[nt][1], v[nt][2], v[nt][3]};
            *(f32x4*)(outv + 16 * nt + 4 * hi) = o;
        }
    }
    if (lane == 0) *oute = (float)eacc;
}

__global__ __launch_bounds__(64, 1) void crf_chain_kernel(
    const float* __restrict__ feats,    // (B,S,L)
    const float* __restrict__ start_t,  // (L)
    const float* __restrict__ end_t,    // (L)
    const float* __restrict__ trans,    // (L,L)
    const int* __restrict__ mask,       // (B,S)
    const int* __restrict__ labels,     // (B,S)
    float* __restrict__ ws)
{
    const int bid = blockIdx.x;
    const int b = bid & 255;
    const int isB = bid >> 8;   // 0 = forward chain, 1 = backward chain
    const int tid = threadIdx.x;

    __shared__ __align__(16) float eRing[4 * LL];  // 2 KB
    __shared__ int lmask[SS];                      // 2 KB

    // stage masks (same-wave LDS; in-order DS makes the RAW safe)
#pragma unroll
    for (int q = 0; q < 8; ++q) lmask[tid + 64 * q] = mask[b * SS + tid + 64 * q];

    const float* fb = feats + (size_t)b * SS * LL;

    float* av = ws;                      // alpha_255 (B,L)
    float* bv = ws + NB * LL;            // beta_255  (B,L)
    float* eFa = ws + 2 * NB * LL;       // fwd exponents (B)
    float* eBa = eFa + NB;               // bwd exponents (B)
    float* lognum = eBa + NB;            // numerator (B)

    if (isB)
        run_chain<1>(tid, fb, start_t, end_t, trans, eRing, lmask, bv + b * LL, eBa + b);
    else
        run_chain<0>(tid, fb, start_t, end_t, trans, eRing, lmask, av + b * LL, eFa + b);

    // ---- numerator (gold path, fp32 exact), bwd block only ----
    if (isB) {
        const int* lb = labels + b * SS;
        const int* mb = mask + b * SS;
        float term = 0.f;
        int cnt = 0;
#pragma unroll
        for (int q = 0; q < 8; ++q) {
            const int tt = tid + 64 * q;
            int l = lb[tt];
            if ((unsigned)l >= LL) l = 0;
            const int m = mb[tt];
            cnt += (m != 0);
            if (tt == 0) {
                term += start_t[l] + fb[l];
            } else if (m) {
                int lp = lb[tt - 1];
                if ((unsigned)lp >= LL) lp = 0;
                term += trans[lp * LL + l] + fb[(size_t)tt * LL + l];
            }
        }
#pragma unroll
        for (int o = 1; o < 64; o <<= 1) {
            term += __shfl_xor(term, o);
            cnt += __shfl_xor(cnt, o);
        }
        if (tid == 0) {
            int sl = cnt - 1;
            sl = sl < 0 ? 0 : (sl >= SS ? SS - 1 : sl);
            int lt = lb[sl];
            if ((unsigned)lt >= LL) lt = 0;
            lognum[b] = term + end_t[lt];
        }
    }
}

// Combine: Z = sum_i alpha_255[i]*beta_255[i] * 2^(eF+eB); loss reduce.
__global__ __launch_bounds__(256) void crf_final_kernel(
    const float* __restrict__ ws, const float* __restrict__ conf,
    float* __restrict__ out)
{
    const int tid = threadIdx.x;  // = batch index
    const float* av = ws;
    const float* bv = ws + NB * LL;
    const float* eFa = ws + 2 * NB * LL;
    const float* eBa = eFa + NB;
    const float* ln = eBa + NB;

    const float4* a4 = (const float4*)(av + tid * LL);
    const float4* b4 = (const float4*)(bv + tid * LL);
    float dot = 0.f;
#pragma unroll 8
    for (int k = 0; k < 32; ++k) {
        float4 a = a4[k], bb = b4[k];
        dot += a.x * bb.x + a.y * bb.y + a.z * bb.z + a.w * bb.w;
    }
    float logZ = logf(dot) + 0.69314718055994531f * (eFa[tid] + eBa[tid]);
    float loss = (logZ - ln[tid]) * conf[tid] * (1.0f / NB);

#pragma unroll
    for (int o = 1; o < 64; o <<= 1) loss += __shfl_xor(loss, o);
    __shared__ float red[4];
    if ((tid & 63) == 0) red[tid >> 6] = loss;
    __syncthreads();
    if (tid == 0) out[0] = red[0] + red[1] + red[2] + red[3];
}

extern "C" void kernel_launch(void* const* d_in, const int* in_sizes, int n_in,
                              void* d_out, int out_size, void* d_ws, size_t ws_size,
                              hipStream_t stream) {
    const float* feats  = (const float*)d_in[0];
    const float* startt = (const float*)d_in[1];
    const float* endt   = (const float*)d_in[2];
    const float* trans  = (const float*)d_in[3];
    const float* conf   = (const float*)d_in[4];
    const int*   mask   = (const int*)d_in[5];
    const int*   labels = (const int*)d_in[6];
    float* out = (float*)d_out;
    float* ws = (float*)d_ws;  // needs (2*256*128 + 3*256) floats = ~266 KB

    hipLaunchKernelGGL(crf_chain_kernel, dim3(2 * NB), dim3(64), 0, stream,
                       feats, startt, endt, trans, mask, labels, ws);
    hipLaunchKernelGGL(crf_final_kernel, dim3(1), dim3(256), 0, stream,
                       ws, conf, out);
}

// Round 7
// 204.408 us; speedup vs baseline: 2.0049x; 1.2356x over previous
//
#include <hip/hip_runtime.h>
#include <hip/hip_bf16.h>
#include <math.h>

#define NB 256
#define SS 512
#define LL 128

typedef short bf16x8 __attribute__((ext_vector_type(8)));
typedef float f32x4 __attribute__((ext_vector_type(4)));

__device__ __forceinline__ short f2bf(float f) {
    __hip_bfloat16 h = __float2bfloat16(f);
    short s;
    __builtin_memcpy(&s, &h, 2);
    return s;
}
__device__ __forceinline__ float bf2f(short s) {
    return __int_as_float(((int)(unsigned short)s) << 16);
}

#define MFMA1632(c, a, bb) \
    c = __builtin_amdgcn_mfma_f32_16x16x32_bf16(a, bb, c, 0, 0, 0)

// Barrier WITHOUT vmcnt drain: per-wave LDS ops (publishes + reads) are
// lgkm-drained, then the 4 waves sync. Global prefetches stay in flight
// across it (round-0's __syncthreads drained vmcnt every round — avoided).
__device__ __forceinline__ void wave_barrier() {
    asm volatile("s_waitcnt lgkmcnt(0)" ::: "memory");
    __builtin_amdgcn_s_barrier();
}

// One BLOCK = 4 waves = one chain (fwd or bwd) of one batch; grid 512
// -> 2 blocks/CU -> 8 waves/CU -> 2 waves/SIMD chip-wide (from different
// chains, so one chain's barrier stall is filled by the other's issue).
// Wave w owns output tiles nt = 2w, 2w+1: per round only 8 MFMAs + ~70 VALU
// per wave (round 5 was 32 MFMAs + ~340 VALU on one wave = issue-bound).
// State crosses waves through a 256-B dbuf LDS image (bf16); exp(T) A-frags
// live in VGPRs (32/wave). Feature exp-ring: 4 slots, duty rotates over
// waves (wave r&3 serves round r+2), global prefetch 4+ rounds deep.
// Rescale: every wave recomputes the same power-of-2 exponent from the
// shared image it already read (round-0-verified, barrier-free).
template <int ISB>
__device__ __forceinline__ void run_chain4(
    const int w, const int lane,
    const float* __restrict__ fb,       // this batch's features (S,L)
    const float* __restrict__ start_t,
    const float* __restrict__ end_t,
    const float* __restrict__ trans,
    short* __restrict__ img,            // LDS [2][LL]
    float* __restrict__ eRing,          // LDS [4][LL]
    const int* __restrict__ lmask,      // LDS [SS]
    float* __restrict__ outv,           // av/bv row (L floats)
    float* __restrict__ oute)           // eFa/eBa slot
{
    const int lo = lane & 15;
    const int hi = lane >> 4;
    const int nt0 = 2 * w, nt1 = 2 * w + 1;

    // ---- A-fragments for this wave's 2 output tiles (standard mapping:
    //      A slot (hi,j) of k-tile kt <-> k = 32kt+8hi+j, row n = 16nt+lo) ----
    // fwd: out[n] = sum_k expT[k][n] u[k];  bwd: out[i] = sum_j expT[i][j] u[j]
    bf16x8 Af0[4], Af1[4];
#pragma unroll
    for (int kt = 0; kt < 4; ++kt) {
        bf16x8 f0, f1;
        const int n0 = 16 * nt0 + lo, n1 = 16 * nt1 + lo;
#pragma unroll
        for (int j = 0; j < 8; ++j) {
            const int k = 32 * kt + 8 * hi + j;
            f0[j] = f2bf(__expf(ISB ? trans[n0 * LL + k] : trans[k * LL + n0]));
            f1[j] = f2bf(__expf(ISB ? trans[n1 * LL + k] : trans[k * LL + n1]));
        }
        Af0[kt] = f0;
        Af1[kt] = f1;
    }

    // ---- state init (D layout: v[n2][j] = row 16*(2w+n2)+4hi+j, cols repl.) ----
    float v[2][4];
#pragma unroll
    for (int n2 = 0; n2 < 2; ++n2)
#pragma unroll
        for (int j = 0; j < 4; ++j) {
            const int p = 16 * (2 * w + n2) + 4 * hi + j;
            v[n2][j] = ISB ? __expf(end_t[p]) : __expf(start_t[p] + fb[p]);
        }

    // ---- bwd: eft_prev prime = exp(f_511) at own positions ----
    f32x4 ep0 = {1.f, 1.f, 1.f, 1.f}, ep1 = ep0;
    if (ISB) {
#pragma unroll
        for (int j = 0; j < 4; ++j) {
            ep0[j] = __expf(fb[(size_t)511 * LL + 16 * nt0 + 4 * hi + j]);
            ep1[j] = __expf(fb[(size_t)511 * LL + 16 * nt1 + 4 * hi + j]);
        }
    }

    // ---- ring prefetch prime: this wave's first duty (round w) writes the
    //      eft row for round w+2: row = fwd w+3 / bwd 508-w ----
    float2 nxt;
    {
        const int row = ISB ? (508 - w) : (w + 3);
        nxt = *(const float2*)(fb + (size_t)row * LL + 2 * lane);
    }

    wave_barrier();   // ring slots 0/1 + lmask (cooperative fills) visible

    int eacc = 0;

    for (int r = 0; r < 256; ++r) {
        // ---- publish own 8 rows (pre-update state; bwd scaled by eft_prev) ----
        short4 p0, p1;
        p0.x = f2bf(ISB ? v[0][0] * ep0[0] : v[0][0]);
        p0.y = f2bf(ISB ? v[0][1] * ep0[1] : v[0][1]);
        p0.z = f2bf(ISB ? v[0][2] * ep0[2] : v[0][2]);
        p0.w = f2bf(ISB ? v[0][3] * ep0[3] : v[0][3]);
        p1.x = f2bf(ISB ? v[1][0] * ep1[0] : v[1][0]);
        p1.y = f2bf(ISB ? v[1][1] * ep1[1] : v[1][1]);
        p1.z = f2bf(ISB ? v[1][2] * ep1[2] : v[1][2]);
        p1.w = f2bf(ISB ? v[1][3] * ep1[3] : v[1][3]);
        short* ib = img + (r & 1) * LL;
        if (lo == 0) {
            *(short4*)(ib + 32 * w + 4 * hi) = p0;
            *(short4*)(ib + 32 * w + 16 + 4 * hi) = p1;
        }
        wave_barrier();  // publish complete + prior-round reads drained

        // ---- full image as B fragments (B slot (hi,j) <-> k=32kt+8hi+j) ----
        bf16x8 Bf[4];
#pragma unroll
        for (int kt = 0; kt < 4; ++kt)
            Bf[kt] = *(const bf16x8*)(ib + 32 * kt + 8 * hi);

        // ---- eft for this round (slot r&3, written 2 rounds ago) ----
        const float* rp = eRing + (r & 3) * LL + 4 * hi;
        f32x4 ec0 = *(const f32x4*)(rp + 16 * nt0);
        f32x4 ec1 = *(const f32x4*)(rp + 16 * nt1);

        // ---- ring duty (wave r&3): write slot for round r+2; prefetch ----
        if (w == (r & 3)) {
            *(float2*)(eRing + ((r + 2) & 3) * LL + 2 * lane) =
                make_float2(__expf(nxt.x), __expf(nxt.y));
            const int rowN = ISB ? (504 - r) : (r + 7);  // in [0,512) always
            nxt = *(const float2*)(fb + (size_t)rowN * LL + 2 * lane);
        }

        int mt = lmask[ISB ? (511 - r) : (r + 1)];
        if (!ISB && r == 255) mt = 0;  // fwd dummy round

        // ---- 8 MFMAs: 2 independent 4-deep accumulator chains ----
        f32x4 cc0 = {0.f, 0.f, 0.f, 0.f}, cc1 = {0.f, 0.f, 0.f, 0.f};
#pragma unroll
        for (int kt = 0; kt < 4; ++kt) {
            MFMA1632(cc0, Af0[kt], Bf[kt]);
            MFMA1632(cc1, Af1[kt], Bf[kt]);
        }

        // ---- epilogue: fwd cand = exp(f_t)*(T^T u); bwd cand = T*pub ----
#pragma unroll
        for (int j = 0; j < 4; ++j) {
            const float c0 = ISB ? cc0[j] : ec0[j] * cc0[j];
            const float c1 = ISB ? cc1[j] : ec1[j] * cc1[j];
            v[0][j] = mt ? c0 : v[0][j];
            v[1][j] = mt ? c1 : v[1][j];
        }

        // ---- rescale every 8 rounds: identical exponent on all waves,
        //      recomputed from the shared image (exact power of 2) ----
        if ((r & 7) == 7) {
            float s = 0.f;
#pragma unroll
            for (int kt = 0; kt < 4; ++kt)
#pragma unroll
                for (int j = 0; j < 8; ++j) s += bf2f(Bf[kt][j]);
            s += __shfl_xor(s, 16);   // combine hi groups (k-partition)
            s += __shfl_xor(s, 32);
            int ex;
            frexpf(s, &ex);
#pragma unroll
            for (int n2 = 0; n2 < 2; ++n2)
#pragma unroll
                for (int j = 0; j < 4; ++j) v[n2][j] = ldexpf(v[n2][j], -ex);
            eacc += ex;
        }

        if (ISB) { ep0 = ec0; ep1 = ec1; }  // eft_prev <- eft_cur
    }

    // ---- export own rows (cols are replicas: lo==0 lanes write) ----
    if (lo == 0) {
        *(f32x4*)(outv + 16 * nt0 + 4 * hi) =
            (f32x4){v[0][0], v[0][1], v[0][2], v[0][3]};
        *(f32x4*)(outv + 16 * nt1 + 4 * hi) =
            (f32x4){v[1][0], v[1][1], v[1][2], v[1][3]};
    }
    if (w == 0 && lane == 0) *oute = (float)eacc;
}

__global__ __launch_bounds__(256, 2) void crf_chain_kernel(
    const float* __restrict__ feats,    // (B,S,L)
    const float* __restrict__ start_t,  // (L)
    const float* __restrict__ end_t,    // (L)
    const float* __restrict__ trans,    // (L,L)
    const int* __restrict__ mask,       // (B,S)
    const int* __restrict__ labels,     // (B,S)
    float* __restrict__ ws)
{
    const int bid = blockIdx.x;
    const int b = bid & 255;
    const int isB = bid >> 8;   // 0 = forward chain, 1 = backward chain
    const int tid = threadIdx.x;
    const int w = tid >> 6;
    const int lane = tid & 63;

    __shared__ __align__(16) short img[2 * LL];     // 512 B, dbuf
    __shared__ __align__(16) float eRing[4 * LL];   // 2 KB
    __shared__ int lmask[SS];                       // 2 KB
    __shared__ float nred[4];
    __shared__ int cred[4];

    const float* fb = feats + (size_t)b * SS * LL;

    // ---- cooperative fills (visibility via the barrier inside run_chain4) ----
    lmask[tid] = mask[b * SS + tid];
    lmask[tid + 256] = mask[b * SS + tid + 256];
    {
        const int slot = tid >> 7;          // ring slots 0,1 = rounds 0,1
        const int e = tid & 127;
        const int row = isB ? (510 - slot) : (1 + slot);
        eRing[slot * LL + e] = __expf(fb[(size_t)row * LL + e]);
    }

    float* av = ws;                      // alpha_255 (B,L)
    float* bv = ws + NB * LL;            // beta_255  (B,L)
    float* eFa = ws + 2 * NB * LL;       // fwd exponents (B)
    float* eBa = eFa + NB;               // bwd exponents (B)
    float* lognum = eBa + NB;            // numerator (B)

    if (isB)
        run_chain4<1>(w, lane, fb, start_t, end_t, trans, img, eRing, lmask,
                      bv + b * LL, eBa + b);
    else
        run_chain4<0>(w, lane, fb, start_t, end_t, trans, img, eRing, lmask,
                      av + b * LL, eFa + b);

    // ---- numerator (gold path, fp32 exact), bwd blocks, 4 waves ----
    if (isB) {
        const int* lb = labels + b * SS;
        const int* mb = mask + b * SS;
        float term = 0.f;
        int cnt = 0;
#pragma unroll
        for (int q = 0; q < 2; ++q) {
            const int tt = tid + 256 * q;
            int l = lb[tt];
            if ((unsigned)l >= LL) l = 0;
            const int m = mb[tt];
            cnt += (m != 0);
            if (tt == 0) {
                term += start_t[l] + fb[l];
            } else if (m) {
                int lp = lb[tt - 1];
                if ((unsigned)lp >= LL) lp = 0;
                term += trans[lp * LL + l] + fb[(size_t)tt * LL + l];
            }
        }
#pragma unroll
        for (int o = 1; o < 64; o <<= 1) {
            term += __shfl_xor(term, o);
            cnt += __shfl_xor(cnt, o);
        }
        if (lane == 0) { nred[w] = term; cred[w] = cnt; }
        __syncthreads();
        if (tid == 0) {
            const float tot = nred[0] + nred[1] + nred[2] + nred[3];
            const int c = cred[0] + cred[1] + cred[2] + cred[3];
            int sl = c - 1;
            sl = sl < 0 ? 0 : (sl >= SS ? SS - 1 : sl);
            int lt = lb[sl];
            if ((unsigned)lt >= LL) lt = 0;
            lognum[b] = tot + end_t[lt];
        }
    }
}

// Combine: Z = sum_i alpha_255[i]*beta_255[i] * 2^(eF+eB); loss reduce.
__global__ __launch_bounds__(256) void crf_final_kernel(
    const float* __restrict__ ws, const float* __restrict__ conf,
    float* __restrict__ out)
{
    const int tid = threadIdx.x;  // = batch index
    const float* av = ws;
    const float* bv = ws + NB * LL;
    const float* eFa = ws + 2 * NB * LL;
    const float* eBa = eFa + NB;
    const float* ln = eBa + NB;

    const float4* a4 = (const float4*)(av + tid * LL);
    const float4* b4 = (const float4*)(bv + tid * LL);
    float dot = 0.f;
#pragma unroll 8
    for (int k = 0; k < 32; ++k) {
        float4 a = a4[k], bb = b4[k];
        dot += a.x * bb.x + a.y * bb.y + a.z * bb.z + a.w * bb.w;
    }
    float logZ = logf(dot) + 0.69314718055994531f * (eFa[tid] + eBa[tid]);
    float loss = (logZ - ln[tid]) * conf[tid] * (1.0f / NB);

#pragma unroll
    for (int o = 1; o < 64; o <<= 1) loss += __shfl_xor(loss, o);
    __shared__ float red[4];
    if ((tid & 63) == 0) red[tid >> 6] = loss;
    __syncthreads();
    if (tid == 0) out[0] = red[0] + red[1] + red[2] + red[3];
}

extern "C" void kernel_launch(void* const* d_in, const int* in_sizes, int n_in,
                              void* d_out, int out_size, void* d_ws, size_t ws_size,
                              hipStream_t stream) {
    const float* feats  = (const float*)d_in[0];
    const float* startt = (const float*)d_in[1];
    const float* endt   = (const float*)d_in[2];
    const float* trans  = (const float*)d_in[3];
    const float* conf   = (const float*)d_in[4];
    const int*   mask   = (const int*)d_in[5];
    const int*   labels = (const int*)d_in[6];
    float* out = (float*)d_out;
    float* ws = (float*)d_ws;  // needs (2*256*128 + 3*256) floats = ~266 KB

    hipLaunchKernelGGL(crf_chain_kernel, dim3(2 * NB), dim3(256), 0, stream,
                       feats, startt, endt, trans, mask, labels, ws);
    hipLaunchKernelGGL(crf_final_kernel, dim3(1), dim3(256), 0, stream,
                       ws, conf, out);
}